// Round 1
// baseline (142.957 us; speedup 1.0000x reference)
//
#include <hip/hip_runtime.h>

// NonOverlappingLocallyConnected1d: out[b,o,n] = sum_{i,k} x[b,i,4n+k]*w[o,i,4n+k] / sqrt(128)
// x: (64,128,4096) f32, w: (128,128,4096) f32, out: (64,128,1024) f32.
// Memory-bound (416 MB min traffic). Strategy: 256 blocks, each owns 4 consecutive n
// and the FULL 64x128 output tile -> x and w each read exactly once from HBM.
// fp32 -> bf16 on the fly, contract (cin,blk) with mfma_f32_16x16x32_bf16.

#define BSZ    64
#define CIN    128
#define COUT   128
#define ODIM   1024
#define DDIM   4096
#define NB     4        // n values per block
#define CI     8        // cins per chunk -> K-chunk = 32
#define NCHUNK (CIN/CI) // 16
#define LROW   40       // padded LDS row length in bf16 (32 data + 8 pad)
#define PX     (64*LROW + 8)   // 2568  x plane stride (bf16), +8 => planes offset by 4 banks
#define PW     (128*LROW + 8)  // 5128  w plane stride (bf16)

typedef short  bf16x8 __attribute__((ext_vector_type(8)));
typedef short  s16x4  __attribute__((ext_vector_type(4)));
typedef float  f32x4  __attribute__((ext_vector_type(4)));

static __device__ __forceinline__ unsigned short f2bf(float f) {
    unsigned int u = __float_as_uint(f);
    // round-to-nearest-even fp32 -> bf16 (inputs are finite normals)
    u += 0x7fffu + ((u >> 16) & 1u);
    return (unsigned short)(u >> 16);
}

__global__ __launch_bounds__(1024, 4)
void nolc_kernel(const float* __restrict__ xg,
                 const float* __restrict__ wg,
                 float* __restrict__ outg) {
    __shared__ short xs[NB * PX];  // [n][b(64)][c(32, padded 40)]
    __shared__ short ws[NB * PW];  // [n][o(128)][c(32, padded 40)]

    const int bid = blockIdx.x;
    // XCD-contiguous n-groups: XCD x gets bn in [32x, 32x+32)
    const int bn  = (bid & 7) * 32 + (bid >> 3);
    const int t    = threadIdx.x;
    const int lane = t & 63;
    const int wave = t >> 6;          // 0..15

    const int dbase = 16 * bn;        // float offset into D for this block

    // wave -> (b-tile, o-quarter): bt in 0..3 (16 b-rows), oq in 0..3 (32 o-cols)
    const int bt = wave & 3;
    const int oq = wave >> 2;
    const int row = lane & 15;
    const int kg  = lane >> 4;        // 0..3

    f32x4 acc[2][4];                  // [o-subtile j][n]
#pragma unroll
    for (int j = 0; j < 2; ++j)
#pragma unroll
        for (int n = 0; n < 4; ++n)
            acc[j][n] = (f32x4){0.f, 0.f, 0.f, 0.f};

    for (int c = 0; c < NCHUNK; ++c) {
        const int i0 = c * CI;

        // ---- stage x chunk: 64 b * 8 ii * 4 n float4 loads (coalesced 64B segments)
#pragma unroll
        for (int it = 0; it < 2; ++it) {
            int L  = it * 1024 + t;       // 0..2047
            int n  = L & 3;
            int ii = (L >> 2) & 7;
            int b  = L >> 5;
            const float4 v = *reinterpret_cast<const float4*>(
                xg + (size_t)(b * CIN + i0 + ii) * DDIM + dbase + 4 * n);
            s16x4 s;
            s[0] = (short)f2bf(v.x); s[1] = (short)f2bf(v.y);
            s[2] = (short)f2bf(v.z); s[3] = (short)f2bf(v.w);
            *reinterpret_cast<s16x4*>(&xs[n * PX + b * LROW + ii * 4]) = s;
        }
        // ---- stage w chunk: 128 o * 8 ii * 4 n
#pragma unroll
        for (int it = 0; it < 4; ++it) {
            int L  = it * 1024 + t;       // 0..4095
            int n  = L & 3;
            int ii = (L >> 2) & 7;
            int o  = L >> 5;
            const float4 v = *reinterpret_cast<const float4*>(
                wg + (size_t)(o * CIN + i0 + ii) * DDIM + dbase + 4 * n);
            s16x4 s;
            s[0] = (short)f2bf(v.x); s[1] = (short)f2bf(v.y);
            s[2] = (short)f2bf(v.z); s[3] = (short)f2bf(v.w);
            *reinterpret_cast<s16x4*>(&ws[n * PW + o * LROW + ii * 4]) = s;
        }
        __syncthreads();

        // ---- MFMA: A rows = b, B cols = o, K = 32 (this chunk)
        const short* xb = &xs[(bt * 16 + row) * LROW + kg * 8];
        const short* wb = &ws[(oq * 32 + row) * LROW + kg * 8];
#pragma unroll
        for (int n = 0; n < 4; ++n) {
            bf16x8 a = *reinterpret_cast<const bf16x8*>(xb + n * PX);
#pragma unroll
            for (int j = 0; j < 2; ++j) {
                bf16x8 bb = *reinterpret_cast<const bf16x8*>(wb + n * PW + j * 16 * LROW);
                acc[j][n] = __builtin_amdgcn_mfma_f32_16x16x32_bf16(a, bb, acc[j][n], 0, 0, 0);
            }
        }
        __syncthreads();
    }

    // ---- epilogue: out[b, o, 4*bn + n], float4 along n
    const float scale = 0.08838834764831845f;  // 1/sqrt(128)
#pragma unroll
    for (int j = 0; j < 2; ++j) {
        const int o = oq * 32 + j * 16 + row;
#pragma unroll
        for (int r = 0; r < 4; ++r) {
            const int b = bt * 16 + kg * 4 + r;
            float4 v;
            v.x = acc[j][0][r] * scale;
            v.y = acc[j][1][r] * scale;
            v.z = acc[j][2][r] * scale;
            v.w = acc[j][3][r] * scale;
            *reinterpret_cast<float4*>(
                outg + ((size_t)b * COUT + o) * ODIM + 4 * bn) = v;
        }
    }
}

extern "C" void kernel_launch(void* const* d_in, const int* in_sizes, int n_in,
                              void* d_out, int out_size, void* d_ws, size_t ws_size,
                              hipStream_t stream) {
    const float* x = (const float*)d_in[0];
    const float* w = (const float*)d_in[1];
    float* out = (float*)d_out;
    nolc_kernel<<<dim3(256), dim3(1024), 0, stream>>>(x, w, out);
}